// Round 2
// baseline (1532.786 us; speedup 1.0000x reference)
//
#include <hip/hip_runtime.h>
#include <hip/hip_bf16.h>

typedef __hip_bfloat16 bf16;
typedef float f32x4 __attribute__((ext_vector_type(4)));
typedef __bf16 bf16x8 __attribute__((ext_vector_type(8)));
typedef short s16x8 __attribute__((ext_vector_type(8)));

#define HDIM 768
#define NHEAD 8
#define BMOL 128
#define NPG 49
#define EPG 144
#define NNODE (BMOL * NPG)     /* 6272 */
#define NEDGE (BMOL * EPG)     /* 18432 */
#define NH 6144                /* NHEAD*HDIM */
#define G3 2304                /* 3*HDIM */

__device__ __forceinline__ float b2f(short s) {
    unsigned int u = ((unsigned int)(unsigned short)s) << 16;
    return __builtin_bit_cast(float, u);
}

__device__ __forceinline__ void async16(const bf16* g, bf16* l) {
    __builtin_amdgcn_global_load_lds(
        (const __attribute__((address_space(1))) void*)g,
        (__attribute__((address_space(3))) void*)l, 16, 0, 0);
}

// ---------------------------------------------------------------------------
// C[M,N] = A[M,K] @ Bt[N,K]^T + bias[N].  A,Bt bf16 row-major, bias f32.
// M,N mult of 128, K mult of 32.  m97-style 128x128 tile, BK=32.
// ---------------------------------------------------------------------------
template <bool OUT_BF16>
__global__ __launch_bounds__(256) void gemm_bt(
    const bf16* __restrict__ A, const bf16* __restrict__ Bt,
    const float* __restrict__ bias, void* __restrict__ Cv,
    int M, int N, int K) {
    __shared__ __align__(16) bf16 lA[128 * 32];
    __shared__ __align__(16) bf16 lB[128 * 32];
    const int tid = threadIdx.x;
    const int lane = tid & 63;
    const int wave = tid >> 6;
    const int l16 = lane & 15;
    const int quad = lane >> 4;
    const int m0 = blockIdx.y * 128;
    const int n0 = blockIdx.x * 128;

    const int rowL = tid >> 2;        // 0..63
    const int kc = (tid & 3) * 8;

    const bf16* gA0 = A + (size_t)(m0 + rowL) * K + kc;
    const bf16* gA1 = gA0 + (size_t)64 * K;
    const bf16* gB0 = Bt + (size_t)(n0 + rowL) * K + kc;
    const bf16* gB1 = gB0 + (size_t)64 * K;
    bf16* lA0 = lA + tid * 8;
    bf16* lA1 = lA + (256 + tid) * 8;
    bf16* lB0 = lB + tid * 8;
    bf16* lB1 = lB + (256 + tid) * 8;

    const int wm0 = (wave >> 1) * 64;
    const int wn0 = (wave & 1) * 64;

    f32x4 acc[4][4];
#pragma unroll
    for (int i = 0; i < 4; ++i)
#pragma unroll
        for (int j = 0; j < 4; ++j) acc[i][j] = (f32x4){0.f, 0.f, 0.f, 0.f};

    for (int k0 = 0; k0 < K; k0 += 32) {
        __syncthreads();
        async16(gA0 + k0, lA0);
        async16(gA1 + k0, lA1);
        async16(gB0 + k0, lB0);
        async16(gB1 + k0, lB1);
        __syncthreads();
        bf16x8 af[4], bfr[4];
#pragma unroll
        for (int i = 0; i < 4; ++i)
            af[i] = *(const bf16x8*)(lA + (wm0 + i * 16 + l16) * 32 + quad * 8);
#pragma unroll
        for (int j = 0; j < 4; ++j)
            bfr[j] = *(const bf16x8*)(lB + (wn0 + j * 16 + l16) * 32 + quad * 8);
#pragma unroll
        for (int i = 0; i < 4; ++i)
#pragma unroll
            for (int j = 0; j < 4; ++j)
                acc[i][j] = __builtin_amdgcn_mfma_f32_16x16x32_bf16(
                    af[i], bfr[j], acc[i][j], 0, 0, 0);
    }

#pragma unroll
    for (int i = 0; i < 4; ++i) {
#pragma unroll
        for (int j = 0; j < 4; ++j) {
            int row = m0 + wm0 + i * 16 + quad * 4;
            int col = n0 + wn0 + j * 16 + l16;
            float bc = bias[col];
#pragma unroll
            for (int r = 0; r < 4; ++r) {
                float v = acc[i][j][r] + bc;
                if (OUT_BF16)
                    ((bf16*)Cv)[(size_t)(row + r) * N + col] = __float2bfloat16(v);
                else
                    ((float*)Cv)[(size_t)(row + r) * N + col] = v;
            }
        }
    }
}

// ---------------------------------------------------------------------------
// Transpose+convert W (K x Nn, f32) -> Wt (Nn x K, bf16), per blockIdx.z.
// ---------------------------------------------------------------------------
__global__ __launch_bounds__(256) void transpose_w(
    const float* __restrict__ W, bf16* __restrict__ Wt, int K, int Nn) {
    __shared__ bf16 tile[64][65];
    const int z = blockIdx.z;
    const float* Wp = W + (size_t)z * K * Nn;
    bf16* Wtp = Wt + (size_t)z * K * Nn;
    const int n0 = blockIdx.x * 64;
    const int k0 = blockIdx.y * 64;
    const int tx = threadIdx.x & 63;
    const int ty = threadIdx.x >> 6;  // 0..3
#pragma unroll
    for (int i = 0; i < 64; i += 4)
        tile[ty + i][tx] = __float2bfloat16(Wp[(size_t)(k0 + ty + i) * Nn + n0 + tx]);
    __syncthreads();
#pragma unroll
    for (int i = 0; i < 64; i += 4)
        Wtp[(size_t)(n0 + ty + i) * K + k0 + tx] = tile[tx][ty + i];
}

// f32 -> bf16 elementwise
__global__ void cvt_kernel(const float* __restrict__ x, bf16* __restrict__ y,
                           int n) {
    int i = blockIdx.x * 256 + threadIdx.x;
    if (i < n) y[i] = __float2bfloat16(x[i]);
}

// ---------------------------------------------------------------------------
// Per-molecule: edge logits -> edge softmax (per dst,head) -> w = a/8.
// grid = BMOL, block = 256.
// ---------------------------------------------------------------------------
__global__ __launch_bounds__(256) void attn_kernel(
    const bf16* __restrict__ fs, const bf16* __restrict__ fd,
    const float* __restrict__ attn_a_t, const int* __restrict__ src,
    const int* __restrict__ dst, float* __restrict__ w) {
    __shared__ float s_a[NHEAD * HDIM];     // 24 KB
    __shared__ float s_logit[EPG * NHEAD];  // 4.5 KB
    __shared__ int s_gs[EPG], s_gd[EPG], s_ld[EPG];
    __shared__ float s_m[NPG * NHEAD], s_inv[NPG * NHEAD];
    const int tid = threadIdx.x;
    const int b = blockIdx.x;

    for (int p = tid; p < NHEAD * HDIM; p += 256) s_a[p] = attn_a_t[p];
    if (tid < EPG) {
        int e = b * EPG + tid;
        int gs = src[e], gd = dst[e];
        s_gs[tid] = gs;
        s_gd[tid] = gd;
        s_ld[tid] = gd - b * NPG;
    }
    __syncthreads();

    const int w4 = tid >> 6;       // wave 0..3
    const int lane = tid & 63;
    const int lo = lane & 31;      // 32-lane subgroup
    const int hp = lane >> 5;      // head half
    for (int le = w4; le < EPG; le += 4) {
        const bf16* pfs = fs + (size_t)s_gs[le] * NH;
        const bf16* pfd = fd + (size_t)s_gd[le] * NH;
#pragma unroll
        for (int hh = 0; hh < 4; ++hh) {
            int h = hp * 4 + hh;
            int base = h * HDIM + lo * 24;
            const s16x8* vs = (const s16x8*)(pfs + base);
            const s16x8* vd = (const s16x8*)(pfd + base);
            float acc = 0.f;
#pragma unroll
            for (int c = 0; c < 3; ++c) {
                s16x8 a8 = vs[c], d8 = vd[c];
#pragma unroll
                for (int u = 0; u < 8; ++u) {
                    float x = b2f(a8[u]) + b2f(d8[u]);
                    x = (x > 0.f) ? x : 0.2f * x;  // leaky_relu 0.2
                    acc += x * s_a[base + c * 8 + u];
                }
            }
#pragma unroll
            for (int off = 16; off; off >>= 1) acc += __shfl_down(acc, off, 32);
            if (lo == 0) s_logit[le * NHEAD + h] = acc;
        }
    }
    __syncthreads();

    // segment max / sum per (local node, head)
    for (int p = tid; p < NPG * NHEAD; p += 256) {
        int n = p >> 3, h = p & 7;
        float m = -3.0e38f;
        for (int le = 0; le < EPG; ++le)
            if (s_ld[le] == n) m = fmaxf(m, s_logit[le * NHEAD + h]);
        float ss = 0.f;
        for (int le = 0; le < EPG; ++le)
            if (s_ld[le] == n) ss += __expf(s_logit[le * NHEAD + h] - m);
        s_m[p] = m;
        s_inv[p] = (ss > 0.f) ? 1.f / ss : 0.f;
    }
    __syncthreads();

    for (int p = tid; p < EPG * NHEAD; p += 256) {
        int le = p >> 3, h = p & 7;
        int ld = s_ld[le];
        float a = __expf(s_logit[p] - s_m[ld * NHEAD + h]) * s_inv[ld * NHEAD + h];
        w[((size_t)b * EPG + le) * NHEAD + h] = 0.125f * a;  // a / heads
    }
}

// attns[t][i] = sum_h w[attn_eids[i]][h]   (== mean over heads of a)
__global__ void attn_out_kernel(const float* __restrict__ w,
                                const int* __restrict__ eids,
                                float* __restrict__ outp) {
    int i = blockIdx.x * 256 + threadIdx.x;  // < 6144
    int e = eids[i];
    float s = 0.f;
#pragma unroll
    for (int h = 0; h < NHEAD; ++h) s += w[(size_t)e * NHEAD + h];
    outp[i] = s;
}

// ---------------------------------------------------------------------------
// h_next[n,j] = sum_{e: dst=n} sum_h w[e,h] * fs[src_e, h*HDIM + j]
// grid = (3 chunks of 256 dims, BMOL), block = 256.
// ---------------------------------------------------------------------------
__global__ __launch_bounds__(256) void aggregate_kernel(
    const bf16* __restrict__ fs, const float* __restrict__ w,
    const int* __restrict__ src, const int* __restrict__ dst,
    bf16* __restrict__ hout) {
    __shared__ float acc[NPG * 256];      // 50 KB
    __shared__ float s_w[EPG * NHEAD];    // 4.5 KB
    __shared__ int s_gs[EPG], s_ld[EPG];
    const int tid = threadIdx.x;
    const int c = blockIdx.x;
    const int b = blockIdx.y;
    if (tid < EPG) {
        int e = b * EPG + tid;
        s_gs[tid] = src[e];
        s_ld[tid] = dst[e] - b * NPG;
    }
    for (int p = tid; p < EPG * NHEAD; p += 256)
        s_w[p] = w[(size_t)b * EPG * NHEAD + p];
    for (int p = tid; p < NPG * 256; p += 256) acc[p] = 0.f;
    __syncthreads();

    const int dim = c * 256 + tid;
    for (int le = 0; le < EPG; ++le) {
        const bf16* p = fs + (size_t)s_gs[le] * NH + dim;
        float sum = 0.f;
#pragma unroll
        for (int h = 0; h < NHEAD; ++h)
            sum += s_w[le * NHEAD + h] * __bfloat162float(p[h * HDIM]);
        acc[s_ld[le] * 256 + tid] += sum;
    }
    __syncthreads();
    for (int n = 0; n < NPG; ++n)
        hout[((size_t)b * NPG + n) * HDIM + dim] =
            __float2bfloat16(acc[n * 256 + tid]);
}

__global__ void gather_x_kernel(const bf16* __restrict__ h,
                                const int* __restrict__ vn,
                                bf16* __restrict__ x) {
    int idx = blockIdx.x * 256 + threadIdx.x;  // < BMOL*HDIM
    int b = idx / HDIM, d = idx - b * HDIM;
    x[idx] = h[(size_t)vn[b] * HDIM + d];
}

__global__ void init_memb_kernel(const float* __restrict__ mf,
                                 float* __restrict__ m32,
                                 bf16* __restrict__ m16) {
    int idx = blockIdx.x * 256 + threadIdx.x;
    float f = mf[idx];
    m32[idx] = f;
    m16[idx] = __float2bfloat16(f);
}

// GRU gates (r,z,n) + relu; updates f32 + bf16 state; writes d_out on last step
__global__ void gru_gate_kernel(const float* __restrict__ gi,
                                const float* __restrict__ gh,
                                float* __restrict__ m32, bf16* __restrict__ m16,
                                float* __restrict__ outp, int last) {
    int idx = blockIdx.x * 256 + threadIdx.x;  // < BMOL*HDIM
    int b = idx / HDIM, d = idx - b * HDIM;
    const float* gib = gi + (size_t)b * G3;
    const float* ghb = gh + (size_t)b * G3;
    float ir = gib[d], iz = gib[HDIM + d], in_ = gib[2 * HDIM + d];
    float hr = ghb[d], hz = ghb[HDIM + d], hn = ghb[2 * HDIM + d];
    float r = 1.f / (1.f + __expf(-(ir + hr)));
    float z = 1.f / (1.f + __expf(-(iz + hz)));
    float n = tanhf(in_ + r * hn);
    float hprev = m32[idx];
    float hnew = (1.f - z) * n + z * hprev;
    hnew = fmaxf(hnew, 0.f);  // relu
    m32[idx] = hnew;
    m16[idx] = __float2bfloat16(hnew);
    if (last) outp[idx] = hnew;
}

// ---------------------------------------------------------------------------
extern "C" void kernel_launch(void* const* d_in, const int* in_sizes, int n_in,
                              void* d_out, int out_size, void* d_ws,
                              size_t ws_size, hipStream_t stream) {
    const float* h_nodes = (const float*)d_in[0];
    const float* mol_feat = (const float*)d_in[1];
    const float* W_src = (const float*)d_in[2];
    const float* b_src = (const float*)d_in[3];
    const float* W_dst = (const float*)d_in[4];
    const float* b_dst = (const float*)d_in[5];
    const float* attn_a = (const float*)d_in[6];
    const float* W_ih = (const float*)d_in[7];
    const float* W_hh = (const float*)d_in[8];
    const float* b_ih = (const float*)d_in[9];
    const float* b_hh = (const float*)d_in[10];
    const int* src = (const int*)d_in[11];
    const int* dst = (const int*)d_in[12];
    const int* vnids = (const int*)d_in[13];
    const int* eids = (const int*)d_in[14];
    float* out = (float*)d_out;

    char* p = (char*)d_ws;
    auto alloc = [&](size_t bytes) {
        char* r = p;
        p += (bytes + 255) & ~(size_t)255;
        return r;
    };
    bf16* wsrcT = (bf16*)alloc((size_t)3 * NH * HDIM * 2);
    bf16* wdstT = (bf16*)alloc((size_t)3 * NH * HDIM * 2);
    bf16* wihB = (bf16*)alloc((size_t)3 * G3 * HDIM * 2);
    bf16* whhB = (bf16*)alloc((size_t)3 * G3 * HDIM * 2);
    bf16* fs = (bf16*)alloc((size_t)NNODE * NH * 2);
    bf16* fd = (bf16*)alloc((size_t)NNODE * NH * 2);
    bf16* h_ws = (bf16*)alloc((size_t)NNODE * HDIM * 2);
    float* w_e = (float*)alloc((size_t)NEDGE * NHEAD * 4);
    bf16* xb = (bf16*)alloc((size_t)BMOL * HDIM * 2);
    float* memb32 = (float*)alloc((size_t)BMOL * HDIM * 4);
    bf16* memb16 = (bf16*)alloc((size_t)BMOL * HDIM * 2);
    float* gi = (float*)alloc((size_t)BMOL * G3 * 4);
    float* gh = (float*)alloc((size_t)BMOL * G3 * 4);

    // one-time weight transpose+convert: (768 x 6144) f32 -> (6144 x 768) bf16
    dim3 tgrid(NH / 64, HDIM / 64, 3);
    transpose_w<<<tgrid, 256, 0, stream>>>(W_src, wsrcT, HDIM, NH);
    transpose_w<<<tgrid, 256, 0, stream>>>(W_dst, wdstT, HDIM, NH);
    // GRU weights: already (N x K) layout, just convert
    {
        int n = 3 * G3 * HDIM;
        cvt_kernel<<<(n + 255) / 256, 256, 0, stream>>>(W_ih, wihB, n);
        cvt_kernel<<<(n + 255) / 256, 256, 0, stream>>>(W_hh, whhB, n);
    }
    {
        int n = NNODE * HDIM;
        cvt_kernel<<<(n + 255) / 256, 256, 0, stream>>>(h_nodes, h_ws, n);
    }
    init_memb_kernel<<<BMOL * HDIM / 256, 256, 0, stream>>>(mol_feat, memb32,
                                                            memb16);

    for (int t = 0; t < 3; ++t) {
        gemm_bt<true><<<dim3(NH / 128, NNODE / 128), 256, 0, stream>>>(
            h_ws, wsrcT + (size_t)t * NH * HDIM, b_src + (size_t)t * NH, fs,
            NNODE, NH, HDIM);
        gemm_bt<true><<<dim3(NH / 128, NNODE / 128), 256, 0, stream>>>(
            h_ws, wdstT + (size_t)t * NH * HDIM, b_dst + (size_t)t * NH, fd,
            NNODE, NH, HDIM);
        attn_kernel<<<BMOL, 256, 0, stream>>>(
            fs, fd, attn_a + (size_t)t * NHEAD * HDIM, src, dst, w_e);
        attn_out_kernel<<<BMOL * 48 / 256, 256, 0, stream>>>(
            w_e, eids, out + BMOL * HDIM + t * BMOL * 48);
        aggregate_kernel<<<dim3(3, BMOL), 256, 0, stream>>>(fs, w_e, src, dst,
                                                            h_ws);
        gather_x_kernel<<<BMOL * HDIM / 256, 256, 0, stream>>>(h_ws, vnids, xb);
        gemm_bt<false><<<dim3(G3 / 128, 1), 256, 0, stream>>>(
            xb, wihB + (size_t)t * G3 * HDIM, b_ih + (size_t)t * G3, gi, BMOL,
            G3, HDIM);
        gemm_bt<false><<<dim3(G3 / 128, 1), 256, 0, stream>>>(
            memb16, whhB + (size_t)t * G3 * HDIM, b_hh + (size_t)t * G3, gh,
            BMOL, G3, HDIM);
        gru_gate_kernel<<<BMOL * HDIM / 256, 256, 0, stream>>>(
            gi, gh, memb32, memb16, out, t == 2);
    }
}

// Round 3
// 1326.095 us; speedup vs baseline: 1.1559x; 1.1559x over previous
//
#include <hip/hip_runtime.h>
#include <hip/hip_bf16.h>

typedef __hip_bfloat16 bf16;
typedef float f32x4 __attribute__((ext_vector_type(4)));
typedef __bf16 bf16x8 __attribute__((ext_vector_type(8)));
typedef short s16x8 __attribute__((ext_vector_type(8)));

#define HDIM 768
#define NHEAD 8
#define BMOL 128
#define NPG 49
#define EPG 144
#define NNODE (BMOL * NPG)     /* 6272 */
#define NEDGE (BMOL * EPG)     /* 18432 */
#define NH 6144                /* NHEAD*HDIM */
#define G3 2304                /* 3*HDIM */

__device__ __forceinline__ float b2f(short s) {
    unsigned int u = ((unsigned int)(unsigned short)s) << 16;
    return __builtin_bit_cast(float, u);
}

__device__ __forceinline__ void async16(const bf16* g, bf16* l) {
    __builtin_amdgcn_global_load_lds(
        (const __attribute__((address_space(1))) void*)g,
        (__attribute__((address_space(3))) void*)l, 16, 0, 0);
}

// ---------------------------------------------------------------------------
// C[M,N] = A[M,K] @ Bt[N,K]^T + bias[N].  A,Bt bf16 row-major, bias f32.
// M,N mult of 128, K mult of 32.  m97-style 128x128 tile, BK=32.
// ---------------------------------------------------------------------------
template <bool OUT_BF16>
__global__ __launch_bounds__(256) void gemm_bt(
    const bf16* __restrict__ A, const bf16* __restrict__ Bt,
    const float* __restrict__ bias, void* __restrict__ Cv,
    int M, int N, int K) {
    __shared__ __align__(16) bf16 lA[128 * 32];
    __shared__ __align__(16) bf16 lB[128 * 32];
    const int tid = threadIdx.x;
    const int lane = tid & 63;
    const int wave = tid >> 6;
    const int l16 = lane & 15;
    const int quad = lane >> 4;
    const int m0 = blockIdx.y * 128;
    const int n0 = blockIdx.x * 128;

    const int rowL = tid >> 2;        // 0..63
    const int kc = (tid & 3) * 8;

    const bf16* gA0 = A + (size_t)(m0 + rowL) * K + kc;
    const bf16* gA1 = gA0 + (size_t)64 * K;
    const bf16* gB0 = Bt + (size_t)(n0 + rowL) * K + kc;
    const bf16* gB1 = gB0 + (size_t)64 * K;
    bf16* lA0 = lA + tid * 8;
    bf16* lA1 = lA + (256 + tid) * 8;
    bf16* lB0 = lB + tid * 8;
    bf16* lB1 = lB + (256 + tid) * 8;

    const int wm0 = (wave >> 1) * 64;
    const int wn0 = (wave & 1) * 64;

    f32x4 acc[4][4];
#pragma unroll
    for (int i = 0; i < 4; ++i)
#pragma unroll
        for (int j = 0; j < 4; ++j) acc[i][j] = (f32x4){0.f, 0.f, 0.f, 0.f};

    for (int k0 = 0; k0 < K; k0 += 32) {
        __syncthreads();
        async16(gA0 + k0, lA0);
        async16(gA1 + k0, lA1);
        async16(gB0 + k0, lB0);
        async16(gB1 + k0, lB1);
        __syncthreads();
        bf16x8 af[4], bfr[4];
#pragma unroll
        for (int i = 0; i < 4; ++i)
            af[i] = *(const bf16x8*)(lA + (wm0 + i * 16 + l16) * 32 + quad * 8);
#pragma unroll
        for (int j = 0; j < 4; ++j)
            bfr[j] = *(const bf16x8*)(lB + (wn0 + j * 16 + l16) * 32 + quad * 8);
#pragma unroll
        for (int i = 0; i < 4; ++i)
#pragma unroll
            for (int j = 0; j < 4; ++j)
                acc[i][j] = __builtin_amdgcn_mfma_f32_16x16x32_bf16(
                    af[i], bfr[j], acc[i][j], 0, 0, 0);
    }

#pragma unroll
    for (int i = 0; i < 4; ++i) {
#pragma unroll
        for (int j = 0; j < 4; ++j) {
            int row = m0 + wm0 + i * 16 + quad * 4;
            int col = n0 + wn0 + j * 16 + l16;
            float bc = bias[col];
#pragma unroll
            for (int r = 0; r < 4; ++r) {
                float v = acc[i][j][r] + bc;
                if (OUT_BF16)
                    ((bf16*)Cv)[(size_t)(row + r) * N + col] = __float2bfloat16(v);
                else
                    ((float*)Cv)[(size_t)(row + r) * N + col] = v;
            }
        }
    }
}

// ---------------------------------------------------------------------------
// Transpose+convert W (K x Nn, f32) -> Wt (Nn x K, bf16), per blockIdx.z.
// ---------------------------------------------------------------------------
__global__ __launch_bounds__(256) void transpose_w(
    const float* __restrict__ W, bf16* __restrict__ Wt, int K, int Nn) {
    __shared__ bf16 tile[64][65];
    const int z = blockIdx.z;
    const float* Wp = W + (size_t)z * K * Nn;
    bf16* Wtp = Wt + (size_t)z * K * Nn;
    const int n0 = blockIdx.x * 64;
    const int k0 = blockIdx.y * 64;
    const int tx = threadIdx.x & 63;
    const int ty = threadIdx.x >> 6;  // 0..3
#pragma unroll
    for (int i = 0; i < 64; i += 4)
        tile[ty + i][tx] = __float2bfloat16(Wp[(size_t)(k0 + ty + i) * Nn + n0 + tx]);
    __syncthreads();
#pragma unroll
    for (int i = 0; i < 64; i += 4)
        Wtp[(size_t)(n0 + ty + i) * K + k0 + tx] = tile[tx][ty + i];
}

// f32 -> bf16 elementwise
__global__ void cvt_kernel(const float* __restrict__ x, bf16* __restrict__ y,
                           int n) {
    int i = blockIdx.x * 256 + threadIdx.x;
    if (i < n) y[i] = __float2bfloat16(x[i]);
}

// ---------------------------------------------------------------------------
// Edge logits: one wave per edge, 8 lanes per head.
// grid = NEDGE/4 blocks of 256.  logit[e,h] = sum_d lrelu(fs+fd)*a[h,d]
// ---------------------------------------------------------------------------
__global__ __launch_bounds__(256) void logits_kernel(
    const bf16* __restrict__ fs, const bf16* __restrict__ fd,
    const float* __restrict__ attn_a_t, const int* __restrict__ src,
    const int* __restrict__ dst, float* __restrict__ logits) {
    __shared__ __align__(16) float s_a[NH];  // 24 KB
    const int tid = threadIdx.x;
    for (int p = tid; p < NH; p += 256) s_a[p] = attn_a_t[p];
    __syncthreads();

    const int wave = tid >> 6;
    const int lane = tid & 63;
    const int e = blockIdx.x * 4 + wave;
    const int gs = src[e], gd = dst[e];
    const bf16* ps = fs + (size_t)gs * NH;
    const bf16* pd = fd + (size_t)gd * NH;
    const int h = lane >> 3;   // head
    const int s = lane & 7;    // sub-lane within head
    const int base = h * HDIM + s * 8;

    float acc = 0.f;
#pragma unroll
    for (int j = 0; j < 12; ++j) {
        const int off = base + j * 64;
        s16x8 a8 = *(const s16x8*)(ps + off);
        s16x8 d8 = *(const s16x8*)(pd + off);
        f32x4 av0 = *(const f32x4*)(s_a + off);
        f32x4 av1 = *(const f32x4*)(s_a + off + 4);
#pragma unroll
        for (int u = 0; u < 4; ++u) {
            float x = b2f(a8[u]) + b2f(d8[u]);
            x = (x > 0.f) ? x : 0.2f * x;
            acc += x * av0[u];
        }
#pragma unroll
        for (int u = 0; u < 4; ++u) {
            float x = b2f(a8[4 + u]) + b2f(d8[4 + u]);
            x = (x > 0.f) ? x : 0.2f * x;
            acc += x * av1[u];
        }
    }
    acc += __shfl_xor(acc, 1);
    acc += __shfl_xor(acc, 2);
    acc += __shfl_xor(acc, 4);
    if (s == 0) logits[(size_t)e * NHEAD + h] = acc;
}

// ---------------------------------------------------------------------------
// Per-molecule edge softmax over precomputed logits -> w = a/8.
// grid = BMOL, block = 256.
// ---------------------------------------------------------------------------
__global__ __launch_bounds__(256) void softmax_kernel(
    const float* __restrict__ logits, const int* __restrict__ dst,
    float* __restrict__ w) {
    __shared__ float s_logit[EPG * NHEAD];
    __shared__ int s_ld[EPG];
    __shared__ float s_m[NPG * NHEAD], s_inv[NPG * NHEAD];
    const int tid = threadIdx.x;
    const int b = blockIdx.x;
    for (int p = tid; p < EPG * NHEAD; p += 256)
        s_logit[p] = logits[(size_t)b * EPG * NHEAD + p];
    if (tid < EPG) s_ld[tid] = dst[b * EPG + tid] - b * NPG;
    __syncthreads();

    for (int p = tid; p < NPG * NHEAD; p += 256) {
        int n = p >> 3, h = p & 7;
        float m = -3.0e38f;
        for (int le = 0; le < EPG; ++le)
            if (s_ld[le] == n) m = fmaxf(m, s_logit[le * NHEAD + h]);
        float ss = 0.f;
        for (int le = 0; le < EPG; ++le)
            if (s_ld[le] == n) ss += __expf(s_logit[le * NHEAD + h] - m);
        s_m[p] = m;
        s_inv[p] = (ss > 0.f) ? 1.f / ss : 0.f;
    }
    __syncthreads();

    for (int p = tid; p < EPG * NHEAD; p += 256) {
        int le = p >> 3, h = p & 7;
        int ld = s_ld[le];
        float a = __expf(s_logit[p] - s_m[ld * NHEAD + h]) * s_inv[ld * NHEAD + h];
        w[(size_t)b * EPG * NHEAD + p] = 0.125f * a;  // a / heads
    }
}

// attns[t][i] = sum_h w[attn_eids[i]][h]   (== mean over heads of a)
__global__ void attn_out_kernel(const float* __restrict__ w,
                                const int* __restrict__ eids,
                                float* __restrict__ outp) {
    int i = blockIdx.x * 256 + threadIdx.x;  // < 6144
    int e = eids[i];
    float s = 0.f;
#pragma unroll
    for (int h = 0; h < NHEAD; ++h) s += w[(size_t)e * NHEAD + h];
    outp[i] = s;
}

// ---------------------------------------------------------------------------
// h_next[n,j] = sum_{e: dst=n} sum_h w[e,h] * fs[src_e, h*HDIM + j]
// grid = (3 chunks of 256 dims, BMOL), block = 256.
// ---------------------------------------------------------------------------
__global__ __launch_bounds__(256) void aggregate_kernel(
    const bf16* __restrict__ fs, const float* __restrict__ w,
    const int* __restrict__ src, const int* __restrict__ dst,
    bf16* __restrict__ hout) {
    __shared__ float acc[NPG * 256];      // 50 KB
    __shared__ float s_w[EPG * NHEAD];    // 4.5 KB
    __shared__ int s_gs[EPG], s_ld[EPG];
    const int tid = threadIdx.x;
    const int c = blockIdx.x;
    const int b = blockIdx.y;
    if (tid < EPG) {
        int e = b * EPG + tid;
        s_gs[tid] = src[e];
        s_ld[tid] = dst[e] - b * NPG;
    }
    for (int p = tid; p < EPG * NHEAD; p += 256)
        s_w[p] = w[(size_t)b * EPG * NHEAD + p];
    for (int p = tid; p < NPG * 256; p += 256) acc[p] = 0.f;
    __syncthreads();

    const int dim = c * 256 + tid;
    for (int le = 0; le < EPG; ++le) {
        const bf16* p = fs + (size_t)s_gs[le] * NH + dim;
        float sum = 0.f;
#pragma unroll
        for (int h = 0; h < NHEAD; ++h)
            sum += s_w[le * NHEAD + h] * __bfloat162float(p[h * HDIM]);
        acc[s_ld[le] * 256 + tid] += sum;
    }
    __syncthreads();
    for (int n = 0; n < NPG; ++n)
        hout[((size_t)b * NPG + n) * HDIM + dim] =
            __float2bfloat16(acc[n * 256 + tid]);
}

__global__ void gather_x_kernel(const bf16* __restrict__ h,
                                const int* __restrict__ vn,
                                bf16* __restrict__ x) {
    int idx = blockIdx.x * 256 + threadIdx.x;  // < BMOL*HDIM
    int b = idx / HDIM, d = idx - b * HDIM;
    x[idx] = h[(size_t)vn[b] * HDIM + d];
}

__global__ void init_memb_kernel(const float* __restrict__ mf,
                                 float* __restrict__ m32,
                                 bf16* __restrict__ m16) {
    int idx = blockIdx.x * 256 + threadIdx.x;
    float f = mf[idx];
    m32[idx] = f;
    m16[idx] = __float2bfloat16(f);
}

// GRU gates (r,z,n) + relu; updates f32 + bf16 state; writes d_out on last step
__global__ void gru_gate_kernel(const float* __restrict__ gi,
                                const float* __restrict__ gh,
                                float* __restrict__ m32, bf16* __restrict__ m16,
                                float* __restrict__ outp, int last) {
    int idx = blockIdx.x * 256 + threadIdx.x;  // < BMOL*HDIM
    int b = idx / HDIM, d = idx - b * HDIM;
    const float* gib = gi + (size_t)b * G3;
    const float* ghb = gh + (size_t)b * G3;
    float ir = gib[d], iz = gib[HDIM + d], in_ = gib[2 * HDIM + d];
    float hr = ghb[d], hz = ghb[HDIM + d], hn = ghb[2 * HDIM + d];
    float r = 1.f / (1.f + __expf(-(ir + hr)));
    float z = 1.f / (1.f + __expf(-(iz + hz)));
    float n = tanhf(in_ + r * hn);
    float hprev = m32[idx];
    float hnew = (1.f - z) * n + z * hprev;
    hnew = fmaxf(hnew, 0.f);  // relu
    m32[idx] = hnew;
    m16[idx] = __float2bfloat16(hnew);
    if (last) outp[idx] = hnew;
}

// ---------------------------------------------------------------------------
extern "C" void kernel_launch(void* const* d_in, const int* in_sizes, int n_in,
                              void* d_out, int out_size, void* d_ws,
                              size_t ws_size, hipStream_t stream) {
    const float* h_nodes = (const float*)d_in[0];
    const float* mol_feat = (const float*)d_in[1];
    const float* W_src = (const float*)d_in[2];
    const float* b_src = (const float*)d_in[3];
    const float* W_dst = (const float*)d_in[4];
    const float* b_dst = (const float*)d_in[5];
    const float* attn_a = (const float*)d_in[6];
    const float* W_ih = (const float*)d_in[7];
    const float* W_hh = (const float*)d_in[8];
    const float* b_ih = (const float*)d_in[9];
    const float* b_hh = (const float*)d_in[10];
    const int* src = (const int*)d_in[11];
    const int* dst = (const int*)d_in[12];
    const int* vnids = (const int*)d_in[13];
    const int* eids = (const int*)d_in[14];
    float* out = (float*)d_out;

    char* p = (char*)d_ws;
    auto alloc = [&](size_t bytes) {
        char* r = p;
        p += (bytes + 255) & ~(size_t)255;
        return r;
    };
    bf16* wsrcT = (bf16*)alloc((size_t)3 * NH * HDIM * 2);
    bf16* wdstT = (bf16*)alloc((size_t)3 * NH * HDIM * 2);
    bf16* wihB = (bf16*)alloc((size_t)3 * G3 * HDIM * 2);
    bf16* whhB = (bf16*)alloc((size_t)3 * G3 * HDIM * 2);
    bf16* fs = (bf16*)alloc((size_t)NNODE * NH * 2);
    bf16* fd = (bf16*)alloc((size_t)NNODE * NH * 2);
    bf16* h_ws = (bf16*)alloc((size_t)NNODE * HDIM * 2);
    float* lg = (float*)alloc((size_t)NEDGE * NHEAD * 4);
    float* w_e = (float*)alloc((size_t)NEDGE * NHEAD * 4);
    bf16* xb = (bf16*)alloc((size_t)BMOL * HDIM * 2);
    float* memb32 = (float*)alloc((size_t)BMOL * HDIM * 4);
    bf16* memb16 = (bf16*)alloc((size_t)BMOL * HDIM * 2);
    float* gi = (float*)alloc((size_t)BMOL * G3 * 4);
    float* gh = (float*)alloc((size_t)BMOL * G3 * 4);

    // one-time weight transpose+convert: (768 x 6144) f32 -> (6144 x 768) bf16
    dim3 tgrid(NH / 64, HDIM / 64, 3);
    transpose_w<<<tgrid, 256, 0, stream>>>(W_src, wsrcT, HDIM, NH);
    transpose_w<<<tgrid, 256, 0, stream>>>(W_dst, wdstT, HDIM, NH);
    // GRU weights: already (N x K) layout, just convert
    {
        int n = 3 * G3 * HDIM;
        cvt_kernel<<<(n + 255) / 256, 256, 0, stream>>>(W_ih, wihB, n);
        cvt_kernel<<<(n + 255) / 256, 256, 0, stream>>>(W_hh, whhB, n);
    }
    {
        int n = NNODE * HDIM;
        cvt_kernel<<<(n + 255) / 256, 256, 0, stream>>>(h_nodes, h_ws, n);
    }
    init_memb_kernel<<<BMOL * HDIM / 256, 256, 0, stream>>>(mol_feat, memb32,
                                                            memb16);

    for (int t = 0; t < 3; ++t) {
        gemm_bt<true><<<dim3(NH / 128, NNODE / 128), 256, 0, stream>>>(
            h_ws, wsrcT + (size_t)t * NH * HDIM, b_src + (size_t)t * NH, fs,
            NNODE, NH, HDIM);
        gemm_bt<true><<<dim3(NH / 128, NNODE / 128), 256, 0, stream>>>(
            h_ws, wdstT + (size_t)t * NH * HDIM, b_dst + (size_t)t * NH, fd,
            NNODE, NH, HDIM);
        logits_kernel<<<NEDGE / 4, 256, 0, stream>>>(
            fs, fd, attn_a + (size_t)t * NHEAD * HDIM, src, dst, lg);
        softmax_kernel<<<BMOL, 256, 0, stream>>>(lg, dst, w_e);
        attn_out_kernel<<<BMOL * 48 / 256, 256, 0, stream>>>(
            w_e, eids, out + BMOL * HDIM + t * BMOL * 48);
        aggregate_kernel<<<dim3(3, BMOL), 256, 0, stream>>>(fs, w_e, src, dst,
                                                            h_ws);
        gather_x_kernel<<<BMOL * HDIM / 256, 256, 0, stream>>>(h_ws, vnids, xb);
        gemm_bt<false><<<dim3(G3 / 128, 1), 256, 0, stream>>>(
            xb, wihB + (size_t)t * G3 * HDIM, b_ih + (size_t)t * G3, gi, BMOL,
            G3, HDIM);
        gemm_bt<false><<<dim3(G3 / 128, 1), 256, 0, stream>>>(
            memb16, whhB + (size_t)t * G3 * HDIM, b_hh + (size_t)t * G3, gh,
            BMOL, G3, HDIM);
        gru_gate_kernel<<<BMOL * HDIM / 256, 256, 0, stream>>>(
            gi, gh, memb32, memb16, out, t == 2);
    }
}

// Round 4
// 1250.490 us; speedup vs baseline: 1.2257x; 1.0605x over previous
//
#include <hip/hip_runtime.h>
#include <hip/hip_bf16.h>

typedef __hip_bfloat16 bf16;
typedef float f32x4 __attribute__((ext_vector_type(4)));
typedef __bf16 bf16x8 __attribute__((ext_vector_type(8)));
typedef short s16x8 __attribute__((ext_vector_type(8)));

#define HDIM 768
#define NHEAD 8
#define BMOL 128
#define NPG 49
#define EPG 144
#define NNODE (BMOL * NPG)     /* 6272 */
#define NEDGE (BMOL * EPG)     /* 18432 */
#define NH 6144                /* NHEAD*HDIM */
#define G3 2304                /* 3*HDIM */

__device__ __forceinline__ float b2f(short s) {
    unsigned int u = ((unsigned int)(unsigned short)s) << 16;
    return __builtin_bit_cast(float, u);
}

__device__ __forceinline__ void async16(const bf16* g, bf16* l) {
    __builtin_amdgcn_global_load_lds(
        (const __attribute__((address_space(1))) void*)g,
        (__attribute__((address_space(3))) void*)l, 16, 0, 0);
}

// ---------------------------------------------------------------------------
// C[M,N] = A[M,K] @ Bt[N,K]^T + bias[N], bf16 out.  BK=64 as two 128x32
// panels (m97 LDS layout per panel -> proven bank profile + lds-contiguity).
// blockIdx.z selects (Bt,bias,C) pair: z=0 -> fs, z=1 -> fd.
// ---------------------------------------------------------------------------
__global__ __launch_bounds__(256) void gemm_bt(
    const bf16* __restrict__ A, const bf16* __restrict__ Bt0,
    const bf16* __restrict__ Bt1, const float* __restrict__ bias0,
    const float* __restrict__ bias1, bf16* __restrict__ C0,
    bf16* __restrict__ C1, int M, int N, int K) {
    __shared__ __align__(16) bf16 lA[2 * 128 * 32];
    __shared__ __align__(16) bf16 lB[2 * 128 * 32];
    const int tid = threadIdx.x;
    const int lane = tid & 63;
    const int wave = tid >> 6;
    const int l16 = lane & 15;
    const int quad = lane >> 4;
    const int m0 = blockIdx.y * 128;
    const int n0 = blockIdx.x * 128;
    const bf16* Bt = blockIdx.z ? Bt1 : Bt0;
    const float* bias = blockIdx.z ? bias1 : bias0;
    bf16* C = blockIdx.z ? C1 : C0;

    const int r64 = tid >> 2;         // 0..63
    const int kc = (tid & 3) * 8;     // 0..24

    const bf16* gA = A + (size_t)(m0 + r64) * K + kc;
    const bf16* gB = Bt + (size_t)(n0 + r64) * K + kc;
    bf16* lAp = lA + tid * 8;
    bf16* lBp = lB + tid * 8;
    const size_t rstep = (size_t)64 * K;

    const int wm0 = (wave >> 1) * 64;
    const int wn0 = (wave & 1) * 64;

    f32x4 acc[4][4];
#pragma unroll
    for (int i = 0; i < 4; ++i)
#pragma unroll
        for (int j = 0; j < 4; ++j) acc[i][j] = (f32x4){0.f, 0.f, 0.f, 0.f};

    for (int k0 = 0; k0 < K; k0 += 64) {
        __syncthreads();
        // panel 0 (k0..k0+31), panel 1 (k0+32..k0+63); each 128 rows
        async16(gA + k0, lAp);
        async16(gA + k0 + rstep, lAp + 2048);
        async16(gA + k0 + 32, lAp + 4096);
        async16(gA + k0 + 32 + rstep, lAp + 6144);
        async16(gB + k0, lBp);
        async16(gB + k0 + rstep, lBp + 2048);
        async16(gB + k0 + 32, lBp + 4096);
        async16(gB + k0 + 32 + rstep, lBp + 6144);
        __syncthreads();
#pragma unroll
        for (int ks = 0; ks < 2; ++ks) {
            bf16x8 af[4], bfr[4];
#pragma unroll
            for (int i = 0; i < 4; ++i)
                af[i] = *(const bf16x8*)(lA + ks * 4096 +
                                         (wm0 + i * 16 + l16) * 32 + quad * 8);
#pragma unroll
            for (int j = 0; j < 4; ++j)
                bfr[j] = *(const bf16x8*)(lB + ks * 4096 +
                                          (wn0 + j * 16 + l16) * 32 + quad * 8);
#pragma unroll
            for (int i = 0; i < 4; ++i)
#pragma unroll
                for (int j = 0; j < 4; ++j)
                    acc[i][j] = __builtin_amdgcn_mfma_f32_16x16x32_bf16(
                        af[i], bfr[j], acc[i][j], 0, 0, 0);
        }
    }

#pragma unroll
    for (int i = 0; i < 4; ++i) {
#pragma unroll
        for (int j = 0; j < 4; ++j) {
            int row = m0 + wm0 + i * 16 + quad * 4;
            int col = n0 + wn0 + j * 16 + l16;
            float bc = bias[col];
#pragma unroll
            for (int r = 0; r < 4; ++r)
                C[(size_t)(row + r) * N + col] =
                    __float2bfloat16(acc[i][j][r] + bc);
        }
    }
}

// ---------------------------------------------------------------------------
// Small-M GEMM for GRU gates: C[128, 2304] f32 = A[128,768] @ Bt[2304,768]^T
// + bias.  Tile 32x256, BK=32, grid (9, 4, 2); z selects (A,Bt,bias,C).
// ---------------------------------------------------------------------------
__global__ __launch_bounds__(256) void gemm_small(
    const bf16* __restrict__ A0, const bf16* __restrict__ A1,
    const bf16* __restrict__ B0, const bf16* __restrict__ B1,
    const float* __restrict__ bias0, const float* __restrict__ bias1,
    float* __restrict__ C0, float* __restrict__ C1) {
    __shared__ __align__(16) bf16 lA[32 * 32];
    __shared__ __align__(16) bf16 lB[256 * 32];
    const int tid = threadIdx.x;
    const int lane = tid & 63;
    const int wave = tid >> 6;
    const int l16 = lane & 15;
    const int quad = lane >> 4;
    const int K = HDIM;
    const int y0 = blockIdx.y * 32;
    const int x0 = blockIdx.x * 256;
    const bf16* A = blockIdx.z ? A1 : A0;
    const bf16* Bt = blockIdx.z ? B1 : B0;
    const float* bias = blockIdx.z ? bias1 : bias0;
    float* C = blockIdx.z ? C1 : C0;

    const bf16* gA = A + (size_t)(y0 + (tid >> 2)) * K + (tid & 3) * 8;
    const bf16* gB = Bt + (size_t)(x0 + (tid >> 2)) * K + (tid & 3) * 8;
    bf16* lAp = lA + tid * 8;
    bf16* lBp = lB + tid * 8;
    const size_t rstep = (size_t)64 * K;

    f32x4 acc[2][4];
#pragma unroll
    for (int i = 0; i < 2; ++i)
#pragma unroll
        for (int j = 0; j < 4; ++j) acc[i][j] = (f32x4){0.f, 0.f, 0.f, 0.f};

    for (int k0 = 0; k0 < K; k0 += 32) {
        __syncthreads();
        if (tid < 128) async16(gA + k0, lAp);
        async16(gB + k0, lBp);
        async16(gB + k0 + rstep, lBp + 2048);
        async16(gB + k0 + 2 * rstep, lBp + 4096);
        async16(gB + k0 + 3 * rstep, lBp + 6144);
        __syncthreads();
        bf16x8 af[2], bfr[4];
#pragma unroll
        for (int i = 0; i < 2; ++i)
            af[i] = *(const bf16x8*)(lA + (i * 16 + l16) * 32 + quad * 8);
#pragma unroll
        for (int j = 0; j < 4; ++j)
            bfr[j] = *(const bf16x8*)(lB + (wave * 64 + j * 16 + l16) * 32 +
                                      quad * 8);
#pragma unroll
        for (int i = 0; i < 2; ++i)
#pragma unroll
            for (int j = 0; j < 4; ++j)
                acc[i][j] = __builtin_amdgcn_mfma_f32_16x16x32_bf16(
                    af[i], bfr[j], acc[i][j], 0, 0, 0);
    }

#pragma unroll
    for (int i = 0; i < 2; ++i) {
#pragma unroll
        for (int j = 0; j < 4; ++j) {
            int row = y0 + i * 16 + quad * 4;
            int col = x0 + wave * 64 + j * 16 + l16;
            float bc = bias[col];
#pragma unroll
            for (int r = 0; r < 4; ++r)
                C[(size_t)(row + r) * G3 + col] = acc[i][j][r] + bc;
        }
    }
}

// ---------------------------------------------------------------------------
// Transpose+convert W (K x Nn, f32) -> Wt (Nn x K, bf16), per blockIdx.z.
// ---------------------------------------------------------------------------
__global__ __launch_bounds__(256) void transpose_w(
    const float* __restrict__ W, bf16* __restrict__ Wt, int K, int Nn) {
    __shared__ bf16 tile[64][65];
    const int z = blockIdx.z;
    const float* Wp = W + (size_t)z * K * Nn;
    bf16* Wtp = Wt + (size_t)z * K * Nn;
    const int n0 = blockIdx.x * 64;
    const int k0 = blockIdx.y * 64;
    const int tx = threadIdx.x & 63;
    const int ty = threadIdx.x >> 6;  // 0..3
#pragma unroll
    for (int i = 0; i < 64; i += 4)
        tile[ty + i][tx] = __float2bfloat16(Wp[(size_t)(k0 + ty + i) * Nn + n0 + tx]);
    __syncthreads();
#pragma unroll
    for (int i = 0; i < 64; i += 4)
        Wtp[(size_t)(n0 + ty + i) * K + k0 + tx] = tile[tx][ty + i];
}

// f32 -> bf16 elementwise
__global__ void cvt_kernel(const float* __restrict__ x, bf16* __restrict__ y,
                           int n) {
    int i = blockIdx.x * 256 + threadIdx.x;
    if (i < n) y[i] = __float2bfloat16(x[i]);
}

// ---------------------------------------------------------------------------
// Edge logits: one wave per edge, 8 lanes per head.
// ---------------------------------------------------------------------------
__global__ __launch_bounds__(256) void logits_kernel(
    const bf16* __restrict__ fs, const bf16* __restrict__ fd,
    const float* __restrict__ attn_a_t, const int* __restrict__ src,
    const int* __restrict__ dst, float* __restrict__ logits) {
    __shared__ __align__(16) float s_a[NH];  // 24 KB
    const int tid = threadIdx.x;
    for (int p = tid; p < NH; p += 256) s_a[p] = attn_a_t[p];
    __syncthreads();

    const int wave = tid >> 6;
    const int lane = tid & 63;
    const int e = blockIdx.x * 4 + wave;
    const int gs = src[e], gd = dst[e];
    const bf16* ps = fs + (size_t)gs * NH;
    const bf16* pd = fd + (size_t)gd * NH;
    const int h = lane >> 3;   // head
    const int s = lane & 7;    // sub-lane within head
    const int base = h * HDIM + s * 8;

    float acc = 0.f;
#pragma unroll
    for (int j = 0; j < 12; ++j) {
        const int off = base + j * 64;
        s16x8 a8 = *(const s16x8*)(ps + off);
        s16x8 d8 = *(const s16x8*)(pd + off);
        f32x4 av0 = *(const f32x4*)(s_a + off);
        f32x4 av1 = *(const f32x4*)(s_a + off + 4);
#pragma unroll
        for (int u = 0; u < 4; ++u) {
            float x = b2f(a8[u]) + b2f(d8[u]);
            x = (x > 0.f) ? x : 0.2f * x;
            acc += x * av0[u];
        }
#pragma unroll
        for (int u = 0; u < 4; ++u) {
            float x = b2f(a8[4 + u]) + b2f(d8[4 + u]);
            x = (x > 0.f) ? x : 0.2f * x;
            acc += x * av1[u];
        }
    }
    acc += __shfl_xor(acc, 1);
    acc += __shfl_xor(acc, 2);
    acc += __shfl_xor(acc, 4);
    if (s == 0) logits[(size_t)e * NHEAD + h] = acc;
}

// ---------------------------------------------------------------------------
// Per-molecule edge softmax over precomputed logits -> w = a/8.
// ---------------------------------------------------------------------------
__global__ __launch_bounds__(256) void softmax_kernel(
    const float* __restrict__ logits, const int* __restrict__ dst,
    float* __restrict__ w) {
    __shared__ float s_logit[EPG * NHEAD];
    __shared__ int s_ld[EPG];
    __shared__ float s_m[NPG * NHEAD], s_inv[NPG * NHEAD];
    const int tid = threadIdx.x;
    const int b = blockIdx.x;
    for (int p = tid; p < EPG * NHEAD; p += 256)
        s_logit[p] = logits[(size_t)b * EPG * NHEAD + p];
    if (tid < EPG) s_ld[tid] = dst[b * EPG + tid] - b * NPG;
    __syncthreads();

    for (int p = tid; p < NPG * NHEAD; p += 256) {
        int n = p >> 3, h = p & 7;
        float m = -3.0e38f;
        for (int le = 0; le < EPG; ++le)
            if (s_ld[le] == n) m = fmaxf(m, s_logit[le * NHEAD + h]);
        float ss = 0.f;
        for (int le = 0; le < EPG; ++le)
            if (s_ld[le] == n) ss += __expf(s_logit[le * NHEAD + h] - m);
        s_m[p] = m;
        s_inv[p] = (ss > 0.f) ? 1.f / ss : 0.f;
    }
    __syncthreads();

    for (int p = tid; p < EPG * NHEAD; p += 256) {
        int le = p >> 3, h = p & 7;
        int ld = s_ld[le];
        float a = __expf(s_logit[p] - s_m[ld * NHEAD + h]) * s_inv[ld * NHEAD + h];
        w[(size_t)b * EPG * NHEAD + p] = 0.125f * a;  // a / heads
    }
}

// attns[t][i] = sum_h w[attn_eids[i]][h]
__global__ void attn_out_kernel(const float* __restrict__ w,
                                const int* __restrict__ eids,
                                float* __restrict__ outp) {
    int i = blockIdx.x * 256 + threadIdx.x;  // < 6144
    int e = eids[i];
    float s = 0.f;
#pragma unroll
    for (int h = 0; h < NHEAD; ++h) s += w[(size_t)e * NHEAD + h];
    outp[i] = s;
}

// ---------------------------------------------------------------------------
// h_next[n,j] = sum_{e: dst=n} sum_h w[e,h] * fs[src_e, h*HDIM + j]
// grid = (6 chunks of 128 dims, BMOL); 2 edge-groups in parallel via
// LDS float atomics (ds_add_f32); 31 KB LDS -> 5 blocks/CU capacity.
// ---------------------------------------------------------------------------
__global__ __launch_bounds__(256) void aggregate_kernel(
    const bf16* __restrict__ fs, const float* __restrict__ w,
    const int* __restrict__ src, const int* __restrict__ dst,
    bf16* __restrict__ hout) {
    __shared__ float acc[NPG * 128];      // 25 KB
    __shared__ float s_w[EPG * NHEAD];    // 4.5 KB
    __shared__ int s_gs[EPG], s_ld[EPG];
    const int tid = threadIdx.x;
    const int c = blockIdx.x;
    const int b = blockIdx.y;
    const int dl = tid & 127;   // dim within chunk
    const int grp = tid >> 7;   // edge group 0/1
    if (tid < EPG) {
        int e = b * EPG + tid;
        s_gs[tid] = src[e];
        s_ld[tid] = dst[e] - b * NPG;
    }
    for (int p = tid; p < EPG * NHEAD; p += 256)
        s_w[p] = w[(size_t)b * EPG * NHEAD + p];
    for (int p = tid; p < NPG * 128; p += 256) acc[p] = 0.f;
    __syncthreads();

    const int dim = c * 128 + dl;
    for (int le2 = 0; le2 < EPG; le2 += 2) {
        const int le = le2 + grp;
        const bf16* p = fs + (size_t)s_gs[le] * NH + dim;
        float sum = 0.f;
#pragma unroll
        for (int h = 0; h < NHEAD; ++h)
            sum += s_w[le * NHEAD + h] * __bfloat162float(p[h * HDIM]);
        atomicAdd(&acc[s_ld[le] * 128 + dl], sum);
    }
    __syncthreads();
    for (int p = tid; p < NPG * 128; p += 256) {
        int n = p >> 7, d = p & 127;
        hout[((size_t)b * NPG + n) * HDIM + c * 128 + d] =
            __float2bfloat16(acc[p]);
    }
}

__global__ void gather_x_kernel(const bf16* __restrict__ h,
                                const int* __restrict__ vn,
                                bf16* __restrict__ x) {
    int idx = blockIdx.x * 256 + threadIdx.x;  // < BMOL*HDIM
    int b = idx / HDIM, d = idx - b * HDIM;
    x[idx] = h[(size_t)vn[b] * HDIM + d];
}

__global__ void init_memb_kernel(const float* __restrict__ mf,
                                 float* __restrict__ m32,
                                 bf16* __restrict__ m16) {
    int idx = blockIdx.x * 256 + threadIdx.x;
    float f = mf[idx];
    m32[idx] = f;
    m16[idx] = __float2bfloat16(f);
}

// GRU gates (r,z,n) + relu
__global__ void gru_gate_kernel(const float* __restrict__ gi,
                                const float* __restrict__ gh,
                                float* __restrict__ m32, bf16* __restrict__ m16,
                                float* __restrict__ outp, int last) {
    int idx = blockIdx.x * 256 + threadIdx.x;  // < BMOL*HDIM
    int b = idx / HDIM, d = idx - b * HDIM;
    const float* gib = gi + (size_t)b * G3;
    const float* ghb = gh + (size_t)b * G3;
    float ir = gib[d], iz = gib[HDIM + d], in_ = gib[2 * HDIM + d];
    float hr = ghb[d], hz = ghb[HDIM + d], hn = ghb[2 * HDIM + d];
    float r = 1.f / (1.f + __expf(-(ir + hr)));
    float z = 1.f / (1.f + __expf(-(iz + hz)));
    float n = tanhf(in_ + r * hn);
    float hprev = m32[idx];
    float hnew = (1.f - z) * n + z * hprev;
    hnew = fmaxf(hnew, 0.f);  // relu
    m32[idx] = hnew;
    m16[idx] = __float2bfloat16(hnew);
    if (last) outp[idx] = hnew;
}

// ---------------------------------------------------------------------------
extern "C" void kernel_launch(void* const* d_in, const int* in_sizes, int n_in,
                              void* d_out, int out_size, void* d_ws,
                              size_t ws_size, hipStream_t stream) {
    const float* h_nodes = (const float*)d_in[0];
    const float* mol_feat = (const float*)d_in[1];
    const float* W_src = (const float*)d_in[2];
    const float* b_src = (const float*)d_in[3];
    const float* W_dst = (const float*)d_in[4];
    const float* b_dst = (const float*)d_in[5];
    const float* attn_a = (const float*)d_in[6];
    const float* W_ih = (const float*)d_in[7];
    const float* W_hh = (const float*)d_in[8];
    const float* b_ih = (const float*)d_in[9];
    const float* b_hh = (const float*)d_in[10];
    const int* src = (const int*)d_in[11];
    const int* dst = (const int*)d_in[12];
    const int* vnids = (const int*)d_in[13];
    const int* eids = (const int*)d_in[14];
    float* out = (float*)d_out;

    char* p = (char*)d_ws;
    auto alloc = [&](size_t bytes) {
        char* r = p;
        p += (bytes + 255) & ~(size_t)255;
        return r;
    };
    bf16* wsrcT = (bf16*)alloc((size_t)3 * NH * HDIM * 2);
    bf16* wdstT = (bf16*)alloc((size_t)3 * NH * HDIM * 2);
    bf16* wihB = (bf16*)alloc((size_t)3 * G3 * HDIM * 2);
    bf16* whhB = (bf16*)alloc((size_t)3 * G3 * HDIM * 2);
    bf16* fs = (bf16*)alloc((size_t)NNODE * NH * 2);
    bf16* fd = (bf16*)alloc((size_t)NNODE * NH * 2);
    bf16* h_ws = (bf16*)alloc((size_t)NNODE * HDIM * 2);
    float* lg = (float*)alloc((size_t)NEDGE * NHEAD * 4);
    float* w_e = (float*)alloc((size_t)NEDGE * NHEAD * 4);
    bf16* xb = (bf16*)alloc((size_t)BMOL * HDIM * 2);
    float* memb32 = (float*)alloc((size_t)BMOL * HDIM * 4);
    bf16* memb16 = (bf16*)alloc((size_t)BMOL * HDIM * 2);
    float* gi = (float*)alloc((size_t)BMOL * G3 * 4);
    float* gh = (float*)alloc((size_t)BMOL * G3 * 4);

    dim3 tgrid(NH / 64, HDIM / 64, 3);
    transpose_w<<<tgrid, 256, 0, stream>>>(W_src, wsrcT, HDIM, NH);
    transpose_w<<<tgrid, 256, 0, stream>>>(W_dst, wdstT, HDIM, NH);
    {
        int n = 3 * G3 * HDIM;
        cvt_kernel<<<(n + 255) / 256, 256, 0, stream>>>(W_ih, wihB, n);
        cvt_kernel<<<(n + 255) / 256, 256, 0, stream>>>(W_hh, whhB, n);
    }
    {
        int n = NNODE * HDIM;
        cvt_kernel<<<(n + 255) / 256, 256, 0, stream>>>(h_nodes, h_ws, n);
    }
    init_memb_kernel<<<BMOL * HDIM / 256, 256, 0, stream>>>(mol_feat, memb32,
                                                            memb16);

    for (int t = 0; t < 3; ++t) {
        gemm_bt<<<dim3(NH / 128, NNODE / 128, 2), 256, 0, stream>>>(
            h_ws, wsrcT + (size_t)t * NH * HDIM, wdstT + (size_t)t * NH * HDIM,
            b_src + (size_t)t * NH, b_dst + (size_t)t * NH, fs, fd, NNODE, NH,
            HDIM);
        logits_kernel<<<NEDGE / 4, 256, 0, stream>>>(
            fs, fd, attn_a + (size_t)t * NHEAD * HDIM, src, dst, lg);
        softmax_kernel<<<BMOL, 256, 0, stream>>>(lg, dst, w_e);
        attn_out_kernel<<<BMOL * 48 / 256, 256, 0, stream>>>(
            w_e, eids, out + BMOL * HDIM + t * BMOL * 48);
        aggregate_kernel<<<dim3(6, BMOL), 256, 0, stream>>>(fs, w_e, src, dst,
                                                            h_ws);
        gather_x_kernel<<<BMOL * HDIM / 256, 256, 0, stream>>>(h_ws, vnids, xb);
        gemm_small<<<dim3(G3 / 256, 4, 2), 256, 0, stream>>>(
            xb, memb16, wihB + (size_t)t * G3 * HDIM,
            whhB + (size_t)t * G3 * HDIM, b_ih + (size_t)t * G3,
            b_hh + (size_t)t * G3, gi, gh);
        gru_gate_kernel<<<BMOL * HDIM / 256, 256, 0, stream>>>(
            gi, gh, memb32, memb16, out, t == 2);
    }
}

// Round 5
// 1222.722 us; speedup vs baseline: 1.2536x; 1.0227x over previous
//
#include <hip/hip_runtime.h>
#include <hip/hip_bf16.h>

typedef __hip_bfloat16 bf16;
typedef float f32x4 __attribute__((ext_vector_type(4)));
typedef __bf16 bf16x8 __attribute__((ext_vector_type(8)));
typedef short s16x8 __attribute__((ext_vector_type(8)));
typedef short s16x2 __attribute__((ext_vector_type(2)));

#define HDIM 768
#define NHEAD 8
#define BMOL 128
#define NPG 49
#define EPG 144
#define NNODE (BMOL * NPG)     /* 6272 */
#define NEDGE (BMOL * EPG)     /* 18432 */
#define NH 6144                /* NHEAD*HDIM */
#define G3 2304                /* 3*HDIM */

__device__ __forceinline__ float b2f(short s) {
    unsigned int u = ((unsigned int)(unsigned short)s) << 16;
    return __builtin_bit_cast(float, u);
}

__device__ __forceinline__ void async16(const bf16* g, bf16* l) {
    __builtin_amdgcn_global_load_lds(
        (const __attribute__((address_space(1))) void*)g,
        (__attribute__((address_space(3))) void*)l, 16, 0, 0);
}

// ---------------------------------------------------------------------------
// C[M,N] = A[M,K] @ Bt[N,K]^T + bias[N], bf16 out.  BK=64 as two 128x32
// panels (m97 LDS layout per panel).  z selects (Bt,bias,C): 0->fs, 1->fd.
// ---------------------------------------------------------------------------
__global__ __launch_bounds__(256) void gemm_bt(
    const bf16* __restrict__ A, const bf16* __restrict__ Bt0,
    const bf16* __restrict__ Bt1, const float* __restrict__ bias0,
    const float* __restrict__ bias1, bf16* __restrict__ C0,
    bf16* __restrict__ C1, int M, int N, int K) {
    __shared__ __align__(16) bf16 lA[2 * 128 * 32];
    __shared__ __align__(16) bf16 lB[2 * 128 * 32];
    const int tid = threadIdx.x;
    const int lane = tid & 63;
    const int wave = tid >> 6;
    const int l16 = lane & 15;
    const int quad = lane >> 4;
    const int m0 = blockIdx.y * 128;
    const int n0 = blockIdx.x * 128;
    const bf16* Bt = blockIdx.z ? Bt1 : Bt0;
    const float* bias = blockIdx.z ? bias1 : bias0;
    bf16* C = blockIdx.z ? C1 : C0;

    const int r64 = tid >> 2;         // 0..63
    const int kc = (tid & 3) * 8;     // 0..24

    const bf16* gA = A + (size_t)(m0 + r64) * K + kc;
    const bf16* gB = Bt + (size_t)(n0 + r64) * K + kc;
    bf16* lAp = lA + tid * 8;
    bf16* lBp = lB + tid * 8;
    const size_t rstep = (size_t)64 * K;

    const int wm0 = (wave >> 1) * 64;
    const int wn0 = (wave & 1) * 64;

    f32x4 acc[4][4];
#pragma unroll
    for (int i = 0; i < 4; ++i)
#pragma unroll
        for (int j = 0; j < 4; ++j) acc[i][j] = (f32x4){0.f, 0.f, 0.f, 0.f};

    for (int k0 = 0; k0 < K; k0 += 64) {
        __syncthreads();
        async16(gA + k0, lAp);
        async16(gA + k0 + rstep, lAp + 2048);
        async16(gA + k0 + 32, lAp + 4096);
        async16(gA + k0 + 32 + rstep, lAp + 6144);
        async16(gB + k0, lBp);
        async16(gB + k0 + rstep, lBp + 2048);
        async16(gB + k0 + 32, lBp + 4096);
        async16(gB + k0 + 32 + rstep, lBp + 6144);
        __syncthreads();
#pragma unroll
        for (int ks = 0; ks < 2; ++ks) {
            bf16x8 af[4], bfr[4];
#pragma unroll
            for (int i = 0; i < 4; ++i)
                af[i] = *(const bf16x8*)(lA + ks * 4096 +
                                         (wm0 + i * 16 + l16) * 32 + quad * 8);
#pragma unroll
            for (int j = 0; j < 4; ++j)
                bfr[j] = *(const bf16x8*)(lB + ks * 4096 +
                                          (wn0 + j * 16 + l16) * 32 + quad * 8);
#pragma unroll
            for (int i = 0; i < 4; ++i)
#pragma unroll
                for (int j = 0; j < 4; ++j)
                    acc[i][j] = __builtin_amdgcn_mfma_f32_16x16x32_bf16(
                        af[i], bfr[j], acc[i][j], 0, 0, 0);
        }
    }

#pragma unroll
    for (int i = 0; i < 4; ++i) {
#pragma unroll
        for (int j = 0; j < 4; ++j) {
            int row = m0 + wm0 + i * 16 + quad * 4;
            int col = n0 + wn0 + j * 16 + l16;
            float bc = bias[col];
#pragma unroll
            for (int r = 0; r < 4; ++r)
                C[(size_t)(row + r) * N + col] =
                    __float2bfloat16(acc[i][j][r] + bc);
        }
    }
}

// ---------------------------------------------------------------------------
// Small-M GEMM for GRU gates: C[128, 2304] f32 = A[128,768] @ Bt[2304,768]^T
// + bias.  Tile 32x256, BK=32, grid (9, 4, 2).  z=0: A = h_ws[vnids[row]]
// (gather fused); z=1: A = memb16.
// ---------------------------------------------------------------------------
__global__ __launch_bounds__(256) void gemm_small(
    const bf16* __restrict__ hws, const int* __restrict__ vnids,
    const bf16* __restrict__ A1, const bf16* __restrict__ B0,
    const bf16* __restrict__ B1, const float* __restrict__ bias0,
    const float* __restrict__ bias1, float* __restrict__ C0,
    float* __restrict__ C1) {
    __shared__ __align__(16) bf16 lA[32 * 32];
    __shared__ __align__(16) bf16 lB[256 * 32];
    const int tid = threadIdx.x;
    const int lane = tid & 63;
    const int wave = tid >> 6;
    const int l16 = lane & 15;
    const int quad = lane >> 4;
    const int K = HDIM;
    const int y0 = blockIdx.y * 32;
    const int x0 = blockIdx.x * 256;
    const bf16* Bt = blockIdx.z ? B1 : B0;
    const float* bias = blockIdx.z ? bias1 : bias0;
    float* C = blockIdx.z ? C1 : C0;

    const int ry = y0 + (tid >> 2);  // 0..127 (valid when tid < 128)
    const bf16* gA;
    if (blockIdx.z)
        gA = A1 + (size_t)ry * K + (tid & 3) * 8;
    else
        gA = hws + (size_t)vnids[ry & 127] * K + (tid & 3) * 8;
    const bf16* gB = Bt + (size_t)(x0 + (tid >> 2)) * K + (tid & 3) * 8;
    bf16* lAp = lA + tid * 8;
    bf16* lBp = lB + tid * 8;
    const size_t rstep = (size_t)64 * K;

    f32x4 acc[2][4];
#pragma unroll
    for (int i = 0; i < 2; ++i)
#pragma unroll
        for (int j = 0; j < 4; ++j) acc[i][j] = (f32x4){0.f, 0.f, 0.f, 0.f};

    for (int k0 = 0; k0 < K; k0 += 32) {
        __syncthreads();
        if (tid < 128) async16(gA + k0, lAp);
        async16(gB + k0, lBp);
        async16(gB + k0 + rstep, lBp + 2048);
        async16(gB + k0 + 2 * rstep, lBp + 4096);
        async16(gB + k0 + 3 * rstep, lBp + 6144);
        __syncthreads();
        bf16x8 af[2], bfr[4];
#pragma unroll
        for (int i = 0; i < 2; ++i)
            af[i] = *(const bf16x8*)(lA + (i * 16 + l16) * 32 + quad * 8);
#pragma unroll
        for (int j = 0; j < 4; ++j)
            bfr[j] = *(const bf16x8*)(lB + (wave * 64 + j * 16 + l16) * 32 +
                                      quad * 8);
#pragma unroll
        for (int i = 0; i < 2; ++i)
#pragma unroll
            for (int j = 0; j < 4; ++j)
                acc[i][j] = __builtin_amdgcn_mfma_f32_16x16x32_bf16(
                    af[i], bfr[j], acc[i][j], 0, 0, 0);
    }

#pragma unroll
    for (int i = 0; i < 2; ++i) {
#pragma unroll
        for (int j = 0; j < 4; ++j) {
            int row = y0 + i * 16 + quad * 4;
            int col = x0 + wave * 64 + j * 16 + l16;
            float bc = bias[col];
#pragma unroll
            for (int r = 0; r < 4; ++r)
                C[(size_t)(row + r) * G3 + col] = acc[i][j][r] + bc;
        }
    }
}

// ---------------------------------------------------------------------------
// Transpose+convert W (K x Nn, f32) -> Wt (Nn x K, bf16), per blockIdx.z.
// ---------------------------------------------------------------------------
__global__ __launch_bounds__(256) void transpose_w(
    const float* __restrict__ W, bf16* __restrict__ Wt, int K, int Nn) {
    __shared__ bf16 tile[64][65];
    const int z = blockIdx.z;
    const float* Wp = W + (size_t)z * K * Nn;
    bf16* Wtp = Wt + (size_t)z * K * Nn;
    const int n0 = blockIdx.x * 64;
    const int k0 = blockIdx.y * 64;
    const int tx = threadIdx.x & 63;
    const int ty = threadIdx.x >> 6;  // 0..3
#pragma unroll
    for (int i = 0; i < 64; i += 4)
        tile[ty + i][tx] = __float2bfloat16(Wp[(size_t)(k0 + ty + i) * Nn + n0 + tx]);
    __syncthreads();
#pragma unroll
    for (int i = 0; i < 64; i += 4)
        Wtp[(size_t)(n0 + ty + i) * K + k0 + tx] = tile[tx][ty + i];
}

// f32 -> bf16 elementwise
__global__ void cvt_kernel(const float* __restrict__ x, bf16* __restrict__ y,
                           int n) {
    int i = blockIdx.x * 256 + threadIdx.x;
    if (i < n) y[i] = __float2bfloat16(x[i]);
}

// ---------------------------------------------------------------------------
// Edge logits: one wave per edge, 8 lanes per head.
// ---------------------------------------------------------------------------
__global__ __launch_bounds__(256) void logits_kernel(
    const bf16* __restrict__ fs, const bf16* __restrict__ fd,
    const float* __restrict__ attn_a_t, const int* __restrict__ src,
    const int* __restrict__ dst, float* __restrict__ logits) {
    __shared__ __align__(16) float s_a[NH];  // 24 KB
    const int tid = threadIdx.x;
    for (int p = tid; p < NH; p += 256) s_a[p] = attn_a_t[p];
    __syncthreads();

    const int wave = tid >> 6;
    const int lane = tid & 63;
    const int e = blockIdx.x * 4 + wave;
    const int gs = src[e], gd = dst[e];
    const bf16* ps = fs + (size_t)gs * NH;
    const bf16* pd = fd + (size_t)gd * NH;
    const int h = lane >> 3;   // head
    const int s = lane & 7;    // sub-lane within head
    const int base = h * HDIM + s * 8;

    float acc = 0.f;
#pragma unroll
    for (int j = 0; j < 12; ++j) {
        const int off = base + j * 64;
        s16x8 a8 = *(const s16x8*)(ps + off);
        s16x8 d8 = *(const s16x8*)(pd + off);
        f32x4 av0 = *(const f32x4*)(s_a + off);
        f32x4 av1 = *(const f32x4*)(s_a + off + 4);
#pragma unroll
        for (int u = 0; u < 4; ++u) {
            float x = b2f(a8[u]) + b2f(d8[u]);
            x = (x > 0.f) ? x : 0.2f * x;
            acc += x * av0[u];
        }
#pragma unroll
        for (int u = 0; u < 4; ++u) {
            float x = b2f(a8[4 + u]) + b2f(d8[4 + u]);
            x = (x > 0.f) ? x : 0.2f * x;
            acc += x * av1[u];
        }
    }
    acc += __shfl_xor(acc, 1);
    acc += __shfl_xor(acc, 2);
    acc += __shfl_xor(acc, 4);
    if (s == 0) logits[(size_t)e * NHEAD + h] = acc;
}

// ---------------------------------------------------------------------------
// Per-molecule edge softmax -> w = a/8; also writes attns output for the
// virtual edges (local edges 96..143, per setup's attn_eids layout).
// ---------------------------------------------------------------------------
__global__ __launch_bounds__(256) void softmax_kernel(
    const float* __restrict__ logits, const int* __restrict__ dst,
    float* __restrict__ w, float* __restrict__ outv) {
    __shared__ float s_logit[EPG * NHEAD];
    __shared__ float s_w[EPG * NHEAD];
    __shared__ int s_ld[EPG];
    __shared__ float s_m[NPG * NHEAD], s_inv[NPG * NHEAD];
    const int tid = threadIdx.x;
    const int b = blockIdx.x;
    for (int p = tid; p < EPG * NHEAD; p += 256)
        s_logit[p] = logits[(size_t)b * EPG * NHEAD + p];
    if (tid < EPG) s_ld[tid] = dst[b * EPG + tid] - b * NPG;
    __syncthreads();

    for (int p = tid; p < NPG * NHEAD; p += 256) {
        int n = p >> 3, h = p & 7;
        float m = -3.0e38f;
        for (int le = 0; le < EPG; ++le)
            if (s_ld[le] == n) m = fmaxf(m, s_logit[le * NHEAD + h]);
        float ss = 0.f;
        for (int le = 0; le < EPG; ++le)
            if (s_ld[le] == n) ss += __expf(s_logit[le * NHEAD + h] - m);
        s_m[p] = m;
        s_inv[p] = (ss > 0.f) ? 1.f / ss : 0.f;
    }
    __syncthreads();

    for (int p = tid; p < EPG * NHEAD; p += 256) {
        int le = p >> 3, h = p & 7;
        int ld = s_ld[le];
        float a =
            0.125f * __expf(s_logit[p] - s_m[ld * NHEAD + h]) * s_inv[ld * NHEAD + h];
        s_w[p] = a;
        w[(size_t)b * EPG * NHEAD + p] = a;
    }
    __syncthreads();
    // attns[t][b*48+i] = sum_h w[edge 96+i, h]
    if (tid < 48) {
        float s = 0.f;
#pragma unroll
        for (int h = 0; h < NHEAD; ++h) s += s_w[(96 + tid) * NHEAD + h];
        outv[b * 48 + tid] = s;
    }
}

// ---------------------------------------------------------------------------
// h_next[n,j] = sum_{e: dst=n} sum_h w[e,h] * fs[src_e, h*HDIM + j]
// grid (6 chunks of 128 dims, BMOL); 4 edge-groups x 64 lanes, 2 dims/thread
// (s16x2 loads: 4 B/lane, 256 B/wave coalesced); LDS f32 atomics.
// ---------------------------------------------------------------------------
__global__ __launch_bounds__(256) void aggregate_kernel(
    const bf16* __restrict__ fs, const float* __restrict__ w,
    const int* __restrict__ src, const int* __restrict__ dst,
    bf16* __restrict__ hout) {
    __shared__ float acc[NPG * 128];      // 25 KB
    __shared__ float s_w[EPG * NHEAD];    // 4.5 KB
    __shared__ int s_gs[EPG], s_ld[EPG];
    const int tid = threadIdx.x;
    const int c = blockIdx.x;
    const int b = blockIdx.y;
    const int grp = tid >> 6;   // edge group 0..3
    const int l = tid & 63;     // dim-pair lane
    if (tid < EPG) {
        int e = b * EPG + tid;
        s_gs[tid] = src[e];
        s_ld[tid] = dst[e] - b * NPG;
    }
    for (int p = tid; p < EPG * NHEAD; p += 256)
        s_w[p] = w[(size_t)b * EPG * NHEAD + p];
    for (int p = tid; p < NPG * 128; p += 256) acc[p] = 0.f;
    __syncthreads();

    const int dim = c * 128 + l * 2;
    for (int le4 = 0; le4 < EPG; le4 += 4) {
        const int le = le4 + grp;
        const bf16* p = fs + (size_t)s_gs[le] * NH + dim;
        float sum0 = 0.f, sum1 = 0.f;
#pragma unroll
        for (int h = 0; h < NHEAD; ++h) {
            s16x2 v = *(const s16x2*)(p + h * HDIM);
            float wv = s_w[le * NHEAD + h];
            sum0 += wv * b2f(v[0]);
            sum1 += wv * b2f(v[1]);
        }
        float* ap = &acc[s_ld[le] * 128 + l * 2];
        atomicAdd(ap, sum0);
        atomicAdd(ap + 1, sum1);
    }
    __syncthreads();
    for (int p = tid; p < NPG * 128; p += 256) {
        int n = p >> 7, d = p & 127;
        hout[((size_t)b * NPG + n) * HDIM + c * 128 + d] =
            __float2bfloat16(acc[p]);
    }
}

__global__ void init_memb_kernel(const float* __restrict__ mf,
                                 float* __restrict__ m32,
                                 bf16* __restrict__ m16) {
    int idx = blockIdx.x * 256 + threadIdx.x;
    float f = mf[idx];
    m32[idx] = f;
    m16[idx] = __float2bfloat16(f);
}

// GRU gates (r,z,n) + relu
__global__ void gru_gate_kernel(const float* __restrict__ gi,
                                const float* __restrict__ gh,
                                float* __restrict__ m32, bf16* __restrict__ m16,
                                float* __restrict__ outp, int last) {
    int idx = blockIdx.x * 256 + threadIdx.x;  // < BMOL*HDIM
    int b = idx / HDIM, d = idx - b * HDIM;
    const float* gib = gi + (size_t)b * G3;
    const float* ghb = gh + (size_t)b * G3;
    float ir = gib[d], iz = gib[HDIM + d], in_ = gib[2 * HDIM + d];
    float hr = ghb[d], hz = ghb[HDIM + d], hn = ghb[2 * HDIM + d];
    float r = 1.f / (1.f + __expf(-(ir + hr)));
    float z = 1.f / (1.f + __expf(-(iz + hz)));
    float n = tanhf(in_ + r * hn);
    float hprev = m32[idx];
    float hnew = (1.f - z) * n + z * hprev;
    hnew = fmaxf(hnew, 0.f);  // relu
    m32[idx] = hnew;
    m16[idx] = __float2bfloat16(hnew);
    if (last) outp[idx] = hnew;
}

// ---------------------------------------------------------------------------
extern "C" void kernel_launch(void* const* d_in, const int* in_sizes, int n_in,
                              void* d_out, int out_size, void* d_ws,
                              size_t ws_size, hipStream_t stream) {
    const float* h_nodes = (const float*)d_in[0];
    const float* mol_feat = (const float*)d_in[1];
    const float* W_src = (const float*)d_in[2];
    const float* b_src = (const float*)d_in[3];
    const float* W_dst = (const float*)d_in[4];
    const float* b_dst = (const float*)d_in[5];
    const float* attn_a = (const float*)d_in[6];
    const float* W_ih = (const float*)d_in[7];
    const float* W_hh = (const float*)d_in[8];
    const float* b_ih = (const float*)d_in[9];
    const float* b_hh = (const float*)d_in[10];
    const int* src = (const int*)d_in[11];
    const int* dst = (const int*)d_in[12];
    const int* vnids = (const int*)d_in[13];
    float* out = (float*)d_out;

    char* p = (char*)d_ws;
    auto alloc = [&](size_t bytes) {
        char* r = p;
        p += (bytes + 255) & ~(size_t)255;
        return r;
    };
    bf16* wsrcT = (bf16*)alloc((size_t)3 * NH * HDIM * 2);
    bf16* wdstT = (bf16*)alloc((size_t)3 * NH * HDIM * 2);
    bf16* wihB = (bf16*)alloc((size_t)3 * G3 * HDIM * 2);
    bf16* whhB = (bf16*)alloc((size_t)3 * G3 * HDIM * 2);
    bf16* fs = (bf16*)alloc((size_t)NNODE * NH * 2);
    bf16* fd = (bf16*)alloc((size_t)NNODE * NH * 2);
    bf16* h_ws = (bf16*)alloc((size_t)NNODE * HDIM * 2);
    float* lg = (float*)alloc((size_t)NEDGE * NHEAD * 4);
    float* w_e = (float*)alloc((size_t)NEDGE * NHEAD * 4);
    float* memb32 = (float*)alloc((size_t)BMOL * HDIM * 4);
    bf16* memb16 = (bf16*)alloc((size_t)BMOL * HDIM * 2);
    float* gi = (float*)alloc((size_t)BMOL * G3 * 4);
    float* gh = (float*)alloc((size_t)BMOL * G3 * 4);

    dim3 tgrid(NH / 64, HDIM / 64, 3);
    transpose_w<<<tgrid, 256, 0, stream>>>(W_src, wsrcT, HDIM, NH);
    transpose_w<<<tgrid, 256, 0, stream>>>(W_dst, wdstT, HDIM, NH);
    {
        int n = 3 * G3 * HDIM;
        cvt_kernel<<<(n + 255) / 256, 256, 0, stream>>>(W_ih, wihB, n);
        cvt_kernel<<<(n + 255) / 256, 256, 0, stream>>>(W_hh, whhB, n);
    }
    {
        int n = NNODE * HDIM;
        cvt_kernel<<<(n + 255) / 256, 256, 0, stream>>>(h_nodes, h_ws, n);
    }
    init_memb_kernel<<<BMOL * HDIM / 256, 256, 0, stream>>>(mol_feat, memb32,
                                                            memb16);

    for (int t = 0; t < 3; ++t) {
        gemm_bt<<<dim3(NH / 128, NNODE / 128, 2), 256, 0, stream>>>(
            h_ws, wsrcT + (size_t)t * NH * HDIM, wdstT + (size_t)t * NH * HDIM,
            b_src + (size_t)t * NH, b_dst + (size_t)t * NH, fs, fd, NNODE, NH,
            HDIM);
        logits_kernel<<<NEDGE / 4, 256, 0, stream>>>(
            fs, fd, attn_a + (size_t)t * NHEAD * HDIM, src, dst, lg);
        softmax_kernel<<<BMOL, 256, 0, stream>>>(
            lg, dst, w_e, out + BMOL * HDIM + t * BMOL * 48);
        aggregate_kernel<<<dim3(6, BMOL), 256, 0, stream>>>(fs, w_e, src, dst,
                                                            h_ws);
        gemm_small<<<dim3(G3 / 256, 4, 2), 256, 0, stream>>>(
            h_ws, vnids, memb16, wihB + (size_t)t * G3 * HDIM,
            whhB + (size_t)t * G3 * HDIM, b_ih + (size_t)t * G3,
            b_hh + (size_t)t * G3, gi, gh);
        gru_gate_kernel<<<BMOL * HDIM / 256, 256, 0, stream>>>(
            gi, gh, memb32, memb16, out, t == 2);
    }
}